// Round 2
// baseline (127.375 us; speedup 1.0000x reference)
//
#include <hip/hip_runtime.h>

// SliceNApply: bilateral-grid trilinear slice + per-pixel 3x4 affine apply.
// FP32 tensors (per reference dtypes). B=4, C=12, D=8, Hg=Wg=16, H=W=1024.
//
// One block = one 64x64 pixel tile of one batch. Tile touches only 3x3
// grid (y,x) cells x 8 z x 12 c -> staged to LDS (fp32, 3.7 KB).
// Per pixel: 2 z-slots x 4 spatial corners x 3 float4 = 24 ds_read_b128.
// z-stride 116 dwords (=20 mod 32): the 8 z-slots land on 8 distinct
// 4-bank groups, so random per-lane z never conflicts; residual cell
// aliasing is at most 2-way (free).

#define SSTRIDE 116   // 9 cells * 12 ch = 108 + 8 pad dwords

__global__ __launch_bounds__(256, 3) void slice_apply_f32(
    const float* __restrict__ grid,   // [4][12][8][16][16]
    const float* __restrict__ guide,  // [4][1][1024][1024]
    const float* __restrict__ fr,     // [4][3][1024][1024]
    float* __restrict__ out)          // [4][3][1024][1024]
{
    __shared__ float lds[8 * SSTRIDE];

    const int b     = blockIdx.y;
    const int tileX = blockIdx.x & 15;
    const int tileY = blockIdx.x >> 4;
    const int t     = threadIdx.x;

    // clamped grid positions this tile can touch
    int px[3], py[3];
#pragma unroll
    for (int j = 0; j < 3; ++j) {
        px[j] = min(max(tileX - 1 + j, 0), 15);
        py[j] = min(max(tileY - 1 + j, 0), 15);
    }

    // ---- stage grid slice into LDS ----
    for (int e = t; e < 8 * 9 * 12; e += 256) {
        const int c    = e % 12;
        const int cell = (e / 12) % 9;
        const int s    = e / 108;
        lds[s * SSTRIDE + cell * 12 + c] =
            grid[((b * 12 + c) * 8 + s) * 256 + py[cell / 3] * 16 + px[cell % 3]];
    }
    __syncthreads();

    // thread -> 4-px strip: 16 threads span the 64-px row, 16 rows/iter, 4 iters
    const int lx4 = (t & 15) * 4;          // local x of strip start (4-aligned)
    const int r   = t >> 4;                // 0..15
    const int bx  = (lx4 >= 32) ? 1 : 0;   // strip never straddles x=32

    const int y0p = tileY << 6;
    const int x0p = tileX << 6;

#pragma unroll
    for (int it = 0; it < 4; ++it) {
        const int ly = (it << 4) + r;      // 0..63
        const int y  = y0p + ly;
        const int by = it >> 1;            // fy0 = tileY-1+by for this half
        const float wy = (ly + 0.5f) * 0.015625f + (0.5f - (float)by);
        const float v1 = wy, v0 = 1.0f - wy;

        const int gofs = (b * 1024 + y) * 1024 + x0p + lx4;
        const int fofs = ((b * 3) * 1024 + y) * 1024 + x0p + lx4;

        const float4 gv  = *reinterpret_cast<const float4*>(guide + gofs);
        const float4 f0v = *reinterpret_cast<const float4*>(fr + fofs);
        const float4 f1v = *reinterpret_cast<const float4*>(fr + fofs + 1048576);
        const float4 f2v = *reinterpret_cast<const float4*>(fr + fofs + 2097152);

        const float gva[4] = {gv.x, gv.y, gv.z, gv.w};
        const float fa0[4] = {f0v.x, f0v.y, f0v.z, f0v.w};
        const float fa1[4] = {f1v.x, f1v.y, f1v.z, f1v.w};
        const float fa2[4] = {f2v.x, f2v.y, f2v.z, f2v.w};

        float o0a[4], o1a[4], o2a[4];

#pragma unroll
        for (int p = 0; p < 4; ++p) {
            const float g  = gva[p];
            const float gz = g * 8.0f - 0.5f;
            int s = (int)floorf(gz);
            s = min(max(s, 0), 7);
            const float wz = fmaxf(gz - (float)s, 0.0f);
            const int s2 = min(s + 1, 7);
            const float zl = 1.0f - wz, zh = wz;

            const float wx = (float)(lx4 + p) * 0.015625f +
                             (0.0078125f + 0.5f - (float)bx);
            const float u1 = wx, u0 = 1.0f - wx;

            float acc[12];
#pragma unroll
            for (int c = 0; c < 12; ++c) acc[c] = 0.0f;

            const int bA = s * SSTRIDE, bB = s2 * SSTRIDE;
#pragma unroll
            for (int dy = 0; dy < 2; ++dy) {
#pragma unroll
                for (int dx = 0; dx < 2; ++dx) {
                    const int co = ((by + dy) * 3 + (bx + dx)) * 12;
                    const float w  = (dy ? v1 : v0) * (dx ? u1 : u0);
                    const float wl = w * zl;
                    const float wh = w * zh;
                    const float4* pA = reinterpret_cast<const float4*>(&lds[bA + co]);
                    const float4* pB = reinterpret_cast<const float4*>(&lds[bB + co]);
#pragma unroll
                    for (int q = 0; q < 3; ++q) {
                        const float4 a  = pA[q];
                        const float4 bb = pB[q];
                        acc[q * 4 + 0] = fmaf(wl, a.x, acc[q * 4 + 0]);
                        acc[q * 4 + 0] = fmaf(wh, bb.x, acc[q * 4 + 0]);
                        acc[q * 4 + 1] = fmaf(wl, a.y, acc[q * 4 + 1]);
                        acc[q * 4 + 1] = fmaf(wh, bb.y, acc[q * 4 + 1]);
                        acc[q * 4 + 2] = fmaf(wl, a.z, acc[q * 4 + 2]);
                        acc[q * 4 + 2] = fmaf(wh, bb.z, acc[q * 4 + 2]);
                        acc[q * 4 + 3] = fmaf(wl, a.w, acc[q * 4 + 3]);
                        acc[q * 4 + 3] = fmaf(wh, bb.w, acc[q * 4 + 3]);
                    }
                }
            }

            const float f0 = fa0[p], f1 = fa1[p], f2 = fa2[p];
            o0a[p] = fmaf(acc[0], f0, fmaf(acc[1], f1, fmaf(acc[2],  f2, acc[3])));
            o1a[p] = fmaf(acc[4], f0, fmaf(acc[5], f1, fmaf(acc[6],  f2, acc[7])));
            o2a[p] = fmaf(acc[8], f0, fmaf(acc[9], f1, fmaf(acc[10], f2, acc[11])));
        }

        const float4 O0 = {o0a[0], o0a[1], o0a[2], o0a[3]};
        const float4 O1 = {o1a[0], o1a[1], o1a[2], o1a[3]};
        const float4 O2 = {o2a[0], o2a[1], o2a[2], o2a[3]};
        *reinterpret_cast<float4*>(out + fofs)           = O0;
        *reinterpret_cast<float4*>(out + fofs + 1048576) = O1;
        *reinterpret_cast<float4*>(out + fofs + 2097152) = O2;
    }
}

extern "C" void kernel_launch(void* const* d_in, const int* in_sizes, int n_in,
                              void* d_out, int out_size, void* d_ws, size_t ws_size,
                              hipStream_t stream) {
    const float* grid  = (const float*)d_in[0];
    const float* guide = (const float*)d_in[1];
    const float* fr    = (const float*)d_in[2];
    float* out = (float*)d_out;

    dim3 g(256, 4);   // 16x16 tiles of 64x64 px, 4 batches
    dim3 blk(256);
    hipLaunchKernelGGL(slice_apply_f32, g, blk, 0, stream, grid, guide, fr, out);
}